// Round 2
// 964.949 us; speedup vs baseline: 1.0136x; 1.0136x over previous
//
#include <hip/hip_runtime.h>
#include <hip/hip_fp16.h>

// All global tensors fp32 (per reference). Intermediates fp16.
// d_ws: wsA [0,64Mi) = q (NCHW h16) then x1 (NHWC h16)
//       wsB [64Mi,128Mi) = k (NCHW h16) then ff1 (NHWC h16)
// d_out doubles as scratch: halfs [0,33554432) = v ; [33554432,67108864) = y (both NCHW h16)
// d_in[1] (mask, mathematically unused) = 2MB scratch:
//   floats [0,262144)  sc: scores [bh][qi][ki] (zeroed, atomicAdd)
//   halfs after that:  wqkv16 [192][64] ; conv wT16 [3][9][64][64] (tap-major)
#define SCALE 0.011048543456039806f   // 1/sqrt(8192)

typedef _Float16 half8 __attribute__((ext_vector_type(8)));
typedef _Float16 h4    __attribute__((ext_vector_type(4)));
typedef float f32x4 __attribute__((ext_vector_type(4)));
typedef unsigned int uint32;

// ---------------- prep: zero score buffer + fp16 weight repack ----------------
__global__ __launch_bounds__(256) void prep_kernel(const float* __restrict__ wq,
                                                   const float* __restrict__ wk,
                                                   const float* __restrict__ wv,
                                                   const float* __restrict__ wo,
                                                   const float* __restrict__ wf1,
                                                   const float* __restrict__ wf2,
                                                   float* __restrict__ scr) {
    int i = blockIdx.x * 256 + threadIdx.x;   // grid 1504 -> 385024 exact
    if (i < 262144) { scr[i] = 0.f; return; }
    __half* wh = (__half*)(scr + 262144);
    int j = i - 262144;
    if (j < 12288) {                           // qkv: wh[gm*64+c], gm=0..191
        int gm = j >> 6, c = j & 63;
        int mtx = gm >> 6, o = gm & 63;
        const float* src = (mtx == 0) ? wq : ((mtx == 1) ? wk : wv);
        wh[j] = __float2half(src[o * 64 + c]);
    } else {                                   // conv: [mtx][tap][o*64+c]
        int r = j - 12288;                     // < 110592
        int mtx = r / 36864;
        int q2 = r - mtx * 36864;
        int tap = q2 >> 12;
        int oc = q2 & 4095;
        int o = oc >> 6, c = oc & 63;
        const float* src = (mtx == 0) ? wo : ((mtx == 1) ? wf1 : wf2);
        wh[j] = __float2half(src[(o * 64 + c) * 9 + tap]);
    }
}

// ---------------- QKV: one M=192,K=64 MFMA GEMM over 256-pixel row tiles ----------------
__global__ __launch_bounds__(512) void qkv_mfma(const float* __restrict__ x,
                                                const __half* __restrict__ wqkv,
                                                const float* __restrict__ bq,
                                                const float* __restrict__ bk,
                                                const float* __restrict__ bv,
                                                __half* __restrict__ q,
                                                __half* __restrict__ k,
                                                __half* __restrict__ v) {
    __shared__ __align__(16) __half Xs[256 * 72];   // [pix][c], stride 72
    __shared__ __align__(16) __half Ws[192 * 72];   // [o192][c]
    int t = threadIdx.x;
    int bx = blockIdx.x;                 // b*256 + row
    int b = bx >> 8, row = bx & 255;
    int hw0 = row << 8;
    int bbase = b << 22;

    for (int i = 0; i < 32; i++) {       // 16384 x-elems fp32->fp16
        int idx = i * 512 + t;
        int c = idx >> 8, p = idx & 255;
        Xs[p * 72 + c] = __float2half(x[bbase + (c << 16) + hw0 + p]);
    }
    const uint32* src = (const uint32*)wqkv;   // 6144 uints
    #pragma unroll
    for (int i = 0; i < 12; i++) {
        int idx = i * 512 + t;
        int o = idx >> 5, c2 = idx & 31;
        *(uint32*)&Ws[o * 72 + c2 * 2] = src[idx];
    }
    __syncthreads();

    int wave = t >> 6, lane = t & 63;
    int l15 = lane & 15, quad = lane >> 4;
    int mg = wave >> 2, ng = wave & 3;   // m-half (6 tiles), n-quarter (4 tiles)
    f32x4 acc[4][6];
    #pragma unroll
    for (int i = 0; i < 4; i++)
        #pragma unroll
        for (int m = 0; m < 6; m++) acc[i][m] = (f32x4){0.f, 0.f, 0.f, 0.f};

    #pragma unroll
    for (int kc = 0; kc < 2; kc++) {
        half8 af[6];
        #pragma unroll
        for (int m = 0; m < 6; m++)
            af[m] = *(const half8*)&Ws[((mg * 6 + m) * 16 + l15) * 72 + kc * 32 + quad * 8];
        #pragma unroll
        for (int i = 0; i < 4; i++) {
            half8 bf = *(const half8*)&Xs[(ng * 64 + i * 16 + l15) * 72 + kc * 32 + quad * 8];
            #pragma unroll
            for (int m = 0; m < 6; m++)
                acc[i][m] = __builtin_amdgcn_mfma_f32_16x16x32_f16(af[m], bf, acc[i][m], 0, 0, 0);
        }
    }
    #pragma unroll
    for (int i = 0; i < 4; i++) {
        int pix = hw0 + ng * 64 + i * 16 + l15;
        #pragma unroll
        for (int m = 0; m < 6; m++) {
            int gm = mg * 6 + m;            // 0..11
            int mtx = gm >> 2;
            int ob = (gm & 3) * 16 + quad * 4;
            __half* dst = (mtx == 0) ? q : ((mtx == 1) ? k : v);
            const float* bb = (mtx == 0) ? bq : ((mtx == 1) ? bk : bv);
            #pragma unroll
            for (int r = 0; r < 4; r++) {
                float z = acc[i][m][r] + bb[ob + r];
                dst[bbase + ((ob + r) << 16) + pix] = __float2half(z);
            }
        }
    }
}

// ---------------- scores partials (unchanged) ----------------
__global__ __launch_bounds__(256) void scores_kernel(const __half* __restrict__ q,
                                                     const __half* __restrict__ k,
                                                     float* __restrict__ sc) {
    __shared__ float Qs[64][68];
    __shared__ float Ks[64][68];
    int ec = blockIdx.x;
    int bh = blockIdx.y;
    int b = bh >> 3, h = bh & 7;
    int cbase = ((b * 64 + h * 8 + ec) << 16);
    int t = threadIdx.x;
    int qg = t >> 4, kg = t & 15;
    float acc[4][4] = {};
    for (int j = 0; j < 16; j++) {
        __syncthreads();
        #pragma unroll
        for (int i = 0; i < 16; i++) {
            int idx = i * 256 + t;
            int wi = idx >> 6;
            int el = idx & 63;
            int eg = j * 64 + el;
            int py = eg >> 5, px = eg & 31;
            int oy = wi >> 3, ox = wi & 7;
            int a = cbase + ((oy * 32 + py) << 8) + ox * 32 + px;
            Qs[el][wi] = __half2float(q[a]);
            Ks[el][wi] = __half2float(k[a]);
        }
        __syncthreads();
        for (int e = 0; e < 64; e++) {
            float4 qv = *(const float4*)&Qs[e][qg * 4];
            float4 kv = *(const float4*)&Ks[e][kg * 4];
            float qa[4] = {qv.x, qv.y, qv.z, qv.w};
            float ka[4] = {kv.x, kv.y, kv.z, kv.w};
            #pragma unroll
            for (int i = 0; i < 4; i++)
                #pragma unroll
                for (int jj = 0; jj < 4; jj++)
                    acc[i][jj] += qa[i] * ka[jj];
        }
    }
    float* dst = sc + bh * 4096;
    #pragma unroll
    for (int i = 0; i < 4; i++)
        #pragma unroll
        for (int jj = 0; jj < 4; jj++)
            atomicAdd(&dst[(qg * 4 + i) * 64 + kg * 4 + jj], acc[i][jj]);
}

// ---------------- softmax (unchanged) ----------------
__global__ __launch_bounds__(64) void softmax_kernel(float* __restrict__ sc) {
    int row = blockIdx.x;
    int ki = threadIdx.x;
    float s = sc[row * 64 + ki] * SCALE;
    float m = s;
    #pragma unroll
    for (int off = 32; off; off >>= 1) m = fmaxf(m, __shfl_xor(m, off));
    float e = __expf(s - m);
    float sum = e;
    #pragma unroll
    for (int off = 32; off; off >>= 1) sum += __shfl_xor(sum, off);
    sc[row * 64 + ki] = e / sum;
}

// ---------------- y = P @ V (unchanged) ----------------
__global__ __launch_bounds__(256) void attnout_kernel(const float* __restrict__ p,
                                                      const __half* __restrict__ v,
                                                      __half* __restrict__ y) {
    __shared__ float Ps[64][65];
    __shared__ float Vs[64][132];
    int dk = blockIdx.x, bh = blockIdx.y;
    int b = bh >> 3, h = bh & 7;
    int cbase = ((b * 64 + h * 8 + dk) << 16);
    int t = threadIdx.x;
    #pragma unroll
    for (int i = 0; i < 16; i++) {
        int idx = i * 256 + t;
        Ps[idx >> 6][idx & 63] = p[bh * 4096 + idx];
    }
    int qg = t >> 4, eg = t & 15;
    for (int sub = 0; sub < 8; sub++) {
        __syncthreads();
        #pragma unroll
        for (int i = 0; i < 32; i++) {
            int idx = i * 256 + t;
            int ki = idx >> 7, el = idx & 127;
            int elg = sub * 128 + el;
            int py = elg >> 5, px = elg & 31;
            int oy = ki >> 3, ox = ki & 7;
            Vs[ki][el] = __half2float(v[cbase + ((oy * 32 + py) << 8) + ox * 32 + px]);
        }
        __syncthreads();
        float acc[4][8] = {};
        for (int ki = 0; ki < 64; ki++) {
            float4 v0 = *(const float4*)&Vs[ki][eg * 8];
            float4 v1 = *(const float4*)&Vs[ki][eg * 8 + 4];
            #pragma unroll
            for (int i = 0; i < 4; i++) {
                float pv = Ps[qg * 4 + i][ki];
                acc[i][0] += pv * v0.x; acc[i][1] += pv * v0.y;
                acc[i][2] += pv * v0.z; acc[i][3] += pv * v0.w;
                acc[i][4] += pv * v1.x; acc[i][5] += pv * v1.y;
                acc[i][6] += pv * v1.z; acc[i][7] += pv * v1.w;
            }
        }
        int elg0 = sub * 128 + eg * 8;
        int py = elg0 >> 5, px = elg0 & 31;
        #pragma unroll
        for (int i = 0; i < 4; i++) {
            int wi = qg * 4 + i;
            int oy = wi >> 3, ox = wi & 7;
            int a = cbase + ((oy * 32 + py) << 8) + ox * 32 + px;
            #pragma unroll
            for (int jj = 0; jj < 8; jj++)
                y[a + jj] = __float2half(acc[i][jj]);
        }
    }
}

// ---------------- conv3x3 v2b: weights-in-regs, single barrier, swizzled X-only LDS ---
// Tile 8x32 outputs/block, 4 waves; wave w computes out-channels [16w,16w+16) over all
// 256 pixels (16 MFMA n-tiles). X tile in LDS as [pix][64ch], 16B chunks XOR-swizzled:
//   half index H(p,c8) = p*64 + ((c8 ^ (p&7))<<3)   (c8 = channel chunk 0..7)
// Both staging writes and compute reads apply the same XOR (both-sides rule) ->
// uniform 8 dwords/bank per wave access, conflict-free.
// IN_NCHW=1: scalar transpose staging (conv_o from y NCHW).
// IN_NCHW=0: NHWC input, reg-staged half8 loads (coalesced 1KB/wave) + ds_write_b128.
// RES: 0 none, 1 fp32 NCHW (x), 2 fp16 NHWC (x1). OUTM: 0 fp16 NHWC, 1 fp32 NCHW.
template <int DIL, int IN_NCHW, int RES, int OUTM>
__global__ __launch_bounds__(256) void conv3x3_v2(const _Float16* __restrict__ in,
                                                  const _Float16* __restrict__ wt,
                                                  const float* __restrict__ bias,
                                                  const void* __restrict__ res,
                                                  void* __restrict__ out) {
    constexpr int TH = 8, TW = 32;
    constexpr int PH = TH + 2 * DIL, PW = TW + 2 * DIL;
    constexpr int NP = PH * PW;
    __shared__ __align__(16) _Float16 Xs[NP * 64];

    int t = threadIdx.x;
    int wave = t >> 6, lane = t & 63;
    int bx = blockIdx.x;
    int tc = bx & 7, tr = (bx >> 3) & 31, b = bx >> 8;
    int x0 = tc * TW, y0 = tr * TH;
    int bb = b << 22;

    if (IN_NCHW) {
        // scalar transpose staging: per wave-instr 8 pixels x 8 channels
        constexpr int PO = (NP + 7) / 8;
        constexpr int SIT = (PO * 8 * 64) / 256;
        for (int i = 0; i < SIT; i++) {
            int s = i * 256 + t;
            int l = s & 63, G = s >> 6;
            int p = (G >> 3) * 8 + (l & 7);
            int c = (G & 7) * 8 + (l >> 3);
            int py = p / PW, px = p - py * PW;
            int gy = y0 + py - DIL; gy = gy < 0 ? -gy : (gy > 255 ? 510 - gy : gy);
            int gx = x0 + px - DIL; gx = gx < 0 ? -gx : (gx > 255 ? 510 - gx : gx);
            _Float16 val = in[bb + (c << 16) + (gy << 8) + gx];
            if (p < NP)
                Xs[(p << 6) + (((c >> 3) ^ (p & 7)) << 3) + (c & 7)] = val;
        }
    } else {
        // NHWC: reg-staged 16B loads, swizzled 16B LDS writes
        constexpr int SLOTS = NP * 8;                 // 16B chunks
        constexpr int SIT = (SLOTS + 255) / 256;
        half8 tmp[SIT];
        #pragma unroll
        for (int i = 0; i < SIT; i++) {
            int s = i * 256 + t;
            int p = s >> 3, c8 = s & 7;
            int py = p / PW, px = p - py * PW;
            int gy = y0 + py - DIL; gy = gy < 0 ? -gy : (gy > 255 ? 510 - gy : gy);
            int gx = x0 + px - DIL; gx = gx < 0 ? -gx : (gx > 255 ? 510 - gx : gx);
            tmp[i] = *(const half8*)(in + bb + (((gy << 8) + gx) << 6) + c8 * 8);
        }
        #pragma unroll
        for (int i = 0; i < SIT; i++) {
            int s = i * 256 + t;
            int p = s >> 3, c8 = s & 7;
            if (s < SLOTS)
                *(half8*)&Xs[(p << 6) + ((c8 ^ (p & 7)) << 3)] = tmp[i];
        }
    }

    int l15 = lane & 15, quad = lane >> 4;
    // weights for this wave's 16 ocs, all 9 taps, in registers (overlaps staging latency)
    half8 af[9][2];
    #pragma unroll
    for (int tap = 0; tap < 9; tap++)
        #pragma unroll
        for (int kc = 0; kc < 2; kc++)
            af[tap][kc] = *(const half8*)&wt[tap * 4096 + (wave * 16 + l15) * 64 + kc * 32 + quad * 8];

    f32x4 acc[16];
    #pragma unroll
    for (int nt = 0; nt < 16; nt++) acc[nt] = (f32x4){0.f, 0.f, 0.f, 0.f};

    __syncthreads();   // single barrier per block

    #pragma unroll
    for (int tap = 0; tap < 9; tap++) {
        const int ky = tap / 3, kx = tap % 3;
        #pragma unroll
        for (int kc = 0; kc < 2; kc++) {
            int cq = kc * 4 + quad;
            #pragma unroll
            for (int nt = 0; nt < 16; nt++) {
                int p = ((nt >> 1) + ky * DIL) * PW + (nt & 1) * 16 + kx * DIL + l15;
                half8 bf = *(const half8*)&Xs[(p << 6) + ((cq ^ (p & 7)) << 3)];
                acc[nt] = __builtin_amdgcn_mfma_f32_16x16x32_f16(af[tap][kc], bf, acc[nt], 0, 0, 0);
            }
        }
    }

    int oc0 = wave * 16 + quad * 4;
    f32x4 b4 = *(const f32x4*)&bias[oc0];
    #pragma unroll
    for (int nt = 0; nt < 16; nt++) {
        int pixg = ((y0 + (nt >> 1)) << 8) + x0 + (nt & 1) * 16 + l15;
        float z[4];
        #pragma unroll
        for (int r = 0; r < 4; r++) {
            float w = acc[nt][r] + b4[r];
            z[r] = w > 0.f ? w : 0.2f * w;
        }
        if (RES == 1) {
            const float* rf = (const float*)res;
            #pragma unroll
            for (int r = 0; r < 4; r++) z[r] += rf[bb + ((oc0 + r) << 16) + pixg];
        } else if (RES == 2) {
            h4 rv = *(const h4*)((const _Float16*)res + bb + (pixg << 6) + oc0);
            #pragma unroll
            for (int r = 0; r < 4; r++) z[r] += (float)rv[r];
        }
        if (OUTM == 0) {
            h4 ov;
            #pragma unroll
            for (int r = 0; r < 4; r++) ov[r] = (_Float16)z[r];
            *(h4*)((_Float16*)out + bb + (pixg << 6) + oc0) = ov;
        } else {
            #pragma unroll
            for (int r = 0; r < 4; r++)
                ((float*)out)[bb + ((oc0 + r) << 16) + pixg] = z[r];
        }
    }
}

extern "C" void kernel_launch(void* const* d_in, const int* in_sizes, int n_in,
                              void* d_out, int out_size, void* d_ws, size_t ws_size,
                              hipStream_t stream) {
    const float* x   = (const float*)d_in[0];
    float*       scr = (float*)d_in[1];        // mask: unused by math -> scratch
    const float* wq  = (const float*)d_in[2];
    const float* bq  = (const float*)d_in[3];
    const float* wk  = (const float*)d_in[4];
    const float* bk  = (const float*)d_in[5];
    const float* wv  = (const float*)d_in[6];
    const float* bv  = (const float*)d_in[7];
    const float* wo  = (const float*)d_in[8];
    const float* bo  = (const float*)d_in[9];
    const float* wf1 = (const float*)d_in[10];
    const float* bf1 = (const float*)d_in[11];
    const float* wf2 = (const float*)d_in[12];
    const float* bf2 = (const float*)d_in[13];

    __half* wsA  = (__half*)d_ws;                        // q (NCHW), then x1 (NHWC)
    __half* wsB  = (__half*)((char*)d_ws + 67108864);    // k (NCHW), then ff1 (NHWC)
    __half* vbuf = (__half*)d_out;                       // v
    __half* ybuf = vbuf + 33554432;                      // y
    float*  outf = (float*)d_out;
    float*  sc   = scr;
    const __half* wh    = (const __half*)(scr + 262144);
    const __half* wqkv  = wh;                            // [192][64]
    const _Float16* wTo = (const _Float16*)(wh + 12288);           // [9][64][64]
    const _Float16* wT1 = (const _Float16*)(wh + 12288 + 36864);
    const _Float16* wT2 = (const _Float16*)(wh + 12288 + 73728);

    prep_kernel<<<1504, 256, 0, stream>>>(wq, wk, wv, wo, wf1, wf2, scr);
    qkv_mfma<<<2048, 512, 0, stream>>>(x, wqkv, bq, bk, bv, wsA, wsB, vbuf);
    scores_kernel<<<dim3(8, 64), 256, 0, stream>>>(wsA, wsB, sc);
    softmax_kernel<<<4096, 64, 0, stream>>>(sc);
    attnout_kernel<<<dim3(8, 64), 256, 0, stream>>>(sc, vbuf, ybuf);
    // x1 = x + lrelu(conv_o(y))        : y NCHW h16 -> x1 NHWC h16 (wsA)
    conv3x3_v2<1, 1, 1, 0><<<2048, 256, 0, stream>>>((const _Float16*)ybuf, wTo, bo,
                                                     (const void*)x, (void*)wsA);
    // ff1 = lrelu(conv_f1(x1, dil=2))  : NHWC -> NHWC h16 (wsB)
    conv3x3_v2<2, 0, 0, 0><<<2048, 256, 0, stream>>>((const _Float16*)wsA, wT1, bf1,
                                                     nullptr, (void*)wsB);
    // out = x1 + lrelu(conv_f2(ff1))   : NHWC -> fp32 NCHW (d_out)
    conv3x3_v2<1, 0, 2, 1><<<2048, 256, 0, stream>>>((const _Float16*)wsB, wT2, bf2,
                                                     (const void*)wsA, (void*)outf);
}